// Round 5
// baseline (666.944 us; speedup 1.0000x reference)
//
#include <hip/hip_runtime.h>
#include <hip/hip_bf16.h>

// GC-LSTM persistent kernel, v3. B=16, T=128, N=256, F=H=128.
// Changes vs v2: (a) lgkm-only barrier (no vmcnt drain -> out stores & x loads
// pipeline across steps), (b) swapped-operand MFMA so each lane owns 4
// consecutive hcols of one row (b64 h-write, dwordx4 out-store, no write bank
// conflicts, bias folded into acc init), (c) x pre-converted to bf16 and loaded
// direct-to-register as MFMA fragments (no x LDS, no per-step f32->bf16).

typedef __bf16 bf16x8 __attribute__((ext_vector_type(8)));
typedef float f32x4 __attribute__((ext_vector_type(4)));

#define PITCH 136  // h LDS row pitch (elems): 272B rows -> <=2-way aliasing on b128/b64

__device__ __forceinline__ unsigned short f2bf(float f) {
  unsigned int u = __float_as_uint(f);
  u += 0x7FFFu + ((u >> 16) & 1u);  // RNE
  return (unsigned short)(u >> 16);
}
__device__ __forceinline__ float sigm(float v) {
  return __fdividef(1.f, 1.f + __expf(-v));
}
__device__ __forceinline__ float tanh_(float v) {
  return 2.f * __fdividef(1.f, 1.f + __expf(-2.f * v)) - 1.f;
}

// Pack combined transposed weights: WT[zc][k], zc = g*128+hc (g: i,f,o,c),
// k<128 -> Wm_g[k][hc], k>=128 -> Wx_g[k-128][hc]. bf16 [512][256] = 256 KB.
__global__ __launch_bounds__(256) void pack_w(
    const float* __restrict__ Wim, const float* __restrict__ Wfm,
    const float* __restrict__ Wom, const float* __restrict__ Wcm,
    const float* __restrict__ Wix, const float* __restrict__ Wfx,
    const float* __restrict__ Wox, const float* __restrict__ Wcx,
    unsigned short* __restrict__ WT) {
  int i = blockIdx.x * 256 + threadIdx.x;  // < 131072
  int zc = i >> 8, k = i & 255;
  int g = zc >> 7, hcol = zc & 127;
  const float* Wm_ = (g == 0) ? Wim : (g == 1) ? Wfm : (g == 2) ? Wom : Wcm;
  const float* Wx_ = (g == 0) ? Wix : (g == 1) ? Wfx : (g == 2) ? Wox : Wcx;
  float v = (k < 128) ? Wm_[k * 128 + hcol] : Wx_[(k - 128) * 128 + hcol];
  WT[i] = f2bf(v);
}

// x f32 -> bf16, same layout. 67108864 elems, 8/thread, 32768 blocks.
__global__ __launch_bounds__(256) void xcvt(const float* __restrict__ x,
                                            unsigned short* __restrict__ xbf) {
  size_t i = ((size_t)blockIdx.x * 256 + threadIdx.x) * 8;
  float4 a = *(const float4*)(x + i);
  float4 b = *(const float4*)(x + i + 4);
  union { unsigned short us[8]; bf16x8 v; } cv;
  cv.us[0] = f2bf(a.x); cv.us[1] = f2bf(a.y);
  cv.us[2] = f2bf(a.z); cv.us[3] = f2bf(a.w);
  cv.us[4] = f2bf(b.x); cv.us[5] = f2bf(b.y);
  cv.us[6] = f2bf(b.z); cv.us[7] = f2bf(b.w);
  *(bf16x8*)(xbf + i) = cv.v;
}

// Persistent LSTM. 256 blocks x 512 threads (8 waves, 2/SIMD).
// Block owns 16 rows (batch bb, nodes n0..n0+16). Wave w owns hcols [16w,16w+16)
// for all 4 gates. MFMA 16x16x32 bf16, operands SWAPPED: D = Wfrag * hfrag ->
// lane (lr,lh) holds z[hrow=lr][hcol = w*16 + lh*4 + r], r=0..3.
__global__ __launch_bounds__(512, 2) void lstm_persist(
    const unsigned short* __restrict__ xbf,
    const unsigned short* __restrict__ WT,
    const float* __restrict__ b_i, const float* __restrict__ b_f,
    const float* __restrict__ b_o, const float* __restrict__ b_c,
    float* __restrict__ out) {
  __shared__ unsigned short hbuf[2][16 * PITCH];

  const int tid = threadIdx.x;
  const int w = tid >> 6, l = tid & 63;
  const int lr = l & 15, lh = l >> 4;
  const int bb = blockIdx.x >> 4;          // batch 0..15
  const int n0 = (blockIdx.x & 15) << 4;   // node start
  const int hc0 = (w << 4) + (lh << 2);    // lane's first h-column

  // Weight A-fragments, resident in VGPRs. Wf[g][kk]: lane holds
  // WT[(g*8+w)*16 + lr][lh*8 + kk*32 .. +8]; kk 0..3 = Wm (k<128), 4..7 = Wx.
  bf16x8 Wf[4][8];
#pragma unroll
  for (int g = 0; g < 4; ++g)
#pragma unroll
    for (int kk = 0; kk < 8; ++kk)
      Wf[g][kk] = *(const bf16x8*)(WT +
          (size_t)((g * 8 + w) * 16 + lr) * 256 + lh * 8 + kk * 32);

  // Bias folded into accumulator init: binit[g][r] = b_g[hc0 + r].
  f32x4 binit[4];
#pragma unroll
  for (int r = 0; r < 4; ++r) {
    binit[0][r] = b_i[hc0 + r];
    binit[1][r] = b_f[hc0 + r];
    binit[2][r] = b_o[hc0 + r];
    binit[3][r] = b_c[hc0 + r];
  }

  // zero hbuf[0]: 16 rows x 128 cols via b64 per thread
  {
    const int zr = tid >> 5, zc = (tid & 31) << 2;
    *(unsigned long long*)(&hbuf[0][zr * PITCH + zc]) = 0ull;
  }

  // x fragment base for this lane: row n0+lr, cols lh*8 + kk*32 (+ t*32768)
  const unsigned short* xlane =
      xbf + ((size_t)(bb * 128) * 256 + n0 + lr) * 128 + lh * 8;

  bf16x8 xA[4], xB[4];
#pragma unroll
  for (int kk = 0; kk < 4; ++kk) xA[kk] = *(const bf16x8*)(xlane + kk * 32);

  float cr[4] = {0.f, 0.f, 0.f, 0.f};
  __syncthreads();

#define STEP(T, XC, XN)                                                        \
  {                                                                            \
    const int cur = (T) & 1, nxt = cur ^ 1;                                    \
    const int tp = ((T) + 1 < 128) ? (T) + 1 : 127;                            \
    _Pragma("unroll")                                                          \
    for (int kk = 0; kk < 4; ++kk)                                             \
      XN[kk] = *(const bf16x8*)(xlane + (size_t)tp * 32768 + kk * 32);         \
    bf16x8 hf[4];                                                              \
    _Pragma("unroll")                                                          \
    for (int kk = 0; kk < 4; ++kk)                                             \
      hf[kk] = *(const bf16x8*)(&hbuf[cur][lr * PITCH + lh * 8 + kk * 32]);    \
    f32x4 acc[4];                                                              \
    _Pragma("unroll")                                                          \
    for (int g = 0; g < 4; ++g) {                                              \
      f32x4 a_ = binit[g];                                                     \
      _Pragma("unroll")                                                        \
      for (int kk = 0; kk < 4; ++kk)                                           \
        a_ = __builtin_amdgcn_mfma_f32_16x16x32_bf16(Wf[g][kk + 4], XC[kk],    \
                                                     a_, 0, 0, 0);             \
      _Pragma("unroll")                                                        \
      for (int kk = 0; kk < 4; ++kk)                                           \
        a_ = __builtin_amdgcn_mfma_f32_16x16x32_bf16(Wf[g][kk], hf[kk],        \
                                                     a_, 0, 0, 0);             \
      acc[g] = a_;                                                             \
    }                                                                          \
    float4 ov;                                                                 \
    unsigned long long hp = 0ull;                                              \
    _Pragma("unroll")                                                          \
    for (int r = 0; r < 4; ++r) {                                              \
      const float iv = sigm(acc[0][r]);                                        \
      const float fv = sigm(acc[1][r]);                                        \
      const float o_ = sigm(acc[2][r]);                                        \
      const float gv = tanh_(acc[3][r]);                                       \
      const float cn = fv * cr[r] + iv * gv;                                   \
      cr[r] = cn;                                                              \
      const float hv = o_ * tanh_(cn);                                         \
      ((float*)&ov)[r] = hv;                                                   \
      hp |= (unsigned long long)f2bf(hv) << (16 * r);                          \
    }                                                                          \
    *(float4*)(out + ((size_t)((T) * 16 + bb) * 256 + n0 + lr) * 128 + hc0) =  \
        ov;                                                                    \
    *(unsigned long long*)(&hbuf[nxt][lr * PITCH + hc0]) = hp;                 \
    asm volatile("s_waitcnt lgkmcnt(0)\n\ts_barrier" ::: "memory");            \
    __builtin_amdgcn_sched_barrier(0);                                         \
  }

  for (int t = 0; t < 128; t += 2) {
    STEP(t, xA, xB)
    STEP(t + 1, xB, xA)
  }
#undef STEP
}

extern "C" void kernel_launch(void* const* d_in, const int* in_sizes, int n_in,
                              void* d_out, int out_size, void* d_ws, size_t ws_size,
                              hipStream_t stream) {
  (void)in_sizes; (void)n_in; (void)out_size; (void)ws_size;
  // setup_inputs order: 0:x 1:Wix 2:Wim 3:Wfx 4:Wfm 5:Wcx 6:Wcm 7:Wox 8:Wom
  //                     9:bi 10:bf 11:bc 12:bo   (note: bc before bo)
  const float* x   = (const float*)d_in[0];
  const float* Wix = (const float*)d_in[1];
  const float* Wim = (const float*)d_in[2];
  const float* Wfx = (const float*)d_in[3];
  const float* Wfm = (const float*)d_in[4];
  const float* Wcx = (const float*)d_in[5];
  const float* Wcm = (const float*)d_in[6];
  const float* Wox = (const float*)d_in[7];
  const float* Wom = (const float*)d_in[8];
  const float* bi  = (const float*)d_in[9];
  const float* bf  = (const float*)d_in[10];
  const float* bc  = (const float*)d_in[11];
  const float* bo  = (const float*)d_in[12];

  char* ws = (char*)d_ws;
  unsigned short* WT  = (unsigned short*)ws;              // 256 KB
  unsigned short* xbf = (unsigned short*)(ws + (1 << 20)); // 134 MB
  float* out = (float*)d_out;

  pack_w<<<512, 256, 0, stream>>>(Wim, Wfm, Wom, Wcm, Wix, Wfx, Wox, Wcx, WT);
  xcvt<<<32768, 256, 0, stream>>>(x, xbf);
  lstm_persist<<<256, 512, 0, stream>>>(xbf, WT, bi, bf, bo, bc, out);
}

// Round 7
// 664.058 us; speedup vs baseline: 1.0043x; 1.0043x over previous
//
#include <hip/hip_runtime.h>
#include <hip/hip_bf16.h>

// GC-LSTM persistent kernel, v4. B=16, T=128, N=256, F=H=128.
// v3 -> v4: pin weight fragments + bias init in VGPRs via empty asm "+v"
// constraints inside the step loop. v3's barrier asm ("memory" clobber)
// invalidated memory-derived values each iteration, so the compiler re-loaded
// all 32 weight fragments from L2 every step (VGPR_Count=108 proved it;
// ~256KB/CU/step of L2 traffic ~ 1900 cyc/step). Pinning forces residency.

typedef __bf16 bf16x8 __attribute__((ext_vector_type(8)));
typedef float f32x4 __attribute__((ext_vector_type(4)));

#define PITCH 136  // h LDS row pitch (elems): 272B rows -> <=2-way aliasing on b64/b128

__device__ __forceinline__ unsigned short f2bf(float f) {
  unsigned int u = __float_as_uint(f);
  u += 0x7FFFu + ((u >> 16) & 1u);  // RNE
  return (unsigned short)(u >> 16);
}
__device__ __forceinline__ float sigm(float v) {
  return __fdividef(1.f, 1.f + __expf(-v));
}
__device__ __forceinline__ float tanh_(float v) {
  return 2.f * __fdividef(1.f, 1.f + __expf(-2.f * v)) - 1.f;
}

// Pack combined transposed weights: WT[zc][k], zc = g*128+hc (g: i,f,o,c),
// k<128 -> Wm_g[k][hc], k>=128 -> Wx_g[k-128][hc]. bf16 [512][256] = 256 KB.
__global__ __launch_bounds__(256) void pack_w(
    const float* __restrict__ Wim, const float* __restrict__ Wfm,
    const float* __restrict__ Wom, const float* __restrict__ Wcm,
    const float* __restrict__ Wix, const float* __restrict__ Wfx,
    const float* __restrict__ Wox, const float* __restrict__ Wcx,
    unsigned short* __restrict__ WT) {
  int i = blockIdx.x * 256 + threadIdx.x;  // < 131072
  int zc = i >> 8, k = i & 255;
  int g = zc >> 7, hcol = zc & 127;
  const float* Wm_ = (g == 0) ? Wim : (g == 1) ? Wfm : (g == 2) ? Wom : Wcm;
  const float* Wx_ = (g == 0) ? Wix : (g == 1) ? Wfx : (g == 2) ? Wox : Wcx;
  float v = (k < 128) ? Wm_[k * 128 + hcol] : Wx_[(k - 128) * 128 + hcol];
  WT[i] = f2bf(v);
}

// x f32 -> bf16, same layout. 67108864 elems, 8/thread, 32768 blocks.
__global__ __launch_bounds__(256) void xcvt(const float* __restrict__ x,
                                            unsigned short* __restrict__ xbf) {
  size_t i = ((size_t)blockIdx.x * 256 + threadIdx.x) * 8;
  float4 a = *(const float4*)(x + i);
  float4 b = *(const float4*)(x + i + 4);
  union { unsigned short us[8]; bf16x8 v; } cv;
  cv.us[0] = f2bf(a.x); cv.us[1] = f2bf(a.y);
  cv.us[2] = f2bf(a.z); cv.us[3] = f2bf(a.w);
  cv.us[4] = f2bf(b.x); cv.us[5] = f2bf(b.y);
  cv.us[6] = f2bf(b.z); cv.us[7] = f2bf(b.w);
  *(bf16x8*)(xbf + i) = cv.v;
}

// Persistent LSTM. 256 blocks x 512 threads (8 waves, 2/SIMD, 1 block/CU).
// Block owns 16 rows (batch bb, nodes n0..n0+16). Wave w owns hcols [16w,16w+16)
// for all 4 gates. MFMA 16x16x32 bf16, operands SWAPPED: D = Wfrag * hfrag ->
// lane (lr,lh) holds z[hrow=lr][hcol = w*16 + lh*4 + r], r=0..3.
__global__ __launch_bounds__(512, 2) void lstm_persist(
    const unsigned short* __restrict__ xbf,
    const unsigned short* __restrict__ WT,
    const float* __restrict__ b_i, const float* __restrict__ b_f,
    const float* __restrict__ b_o, const float* __restrict__ b_c,
    float* __restrict__ out) {
  __shared__ unsigned short hbuf[2][16 * PITCH];

  const int tid = threadIdx.x;
  const int w = tid >> 6, l = tid & 63;
  const int lr = l & 15, lh = l >> 4;
  const int bb = blockIdx.x >> 4;          // batch 0..15
  const int n0 = (blockIdx.x & 15) << 4;   // node start
  const int hc0 = (w << 4) + (lh << 2);    // lane's first h-column

  // Weight A-fragments, resident in VGPRs. Wf[g][kk]: lane holds
  // WT[(g*8+w)*16 + lr][lh*8 + kk*32 .. +8]; kk 0..3 = Wm (k<128), 4..7 = Wx.
  bf16x8 Wf[4][8];
#pragma unroll
  for (int g = 0; g < 4; ++g)
#pragma unroll
    for (int kk = 0; kk < 8; ++kk)
      Wf[g][kk] = *(const bf16x8*)(WT +
          (size_t)((g * 8 + w) * 16 + lr) * 256 + lh * 8 + kk * 32);

  // Bias folded into accumulator init: binit[g][r] = b_g[hc0 + r].
  f32x4 binit[4];
#pragma unroll
  for (int r = 0; r < 4; ++r) {
    binit[0][r] = b_i[hc0 + r];
    binit[1][r] = b_f[hc0 + r];
    binit[2][r] = b_o[hc0 + r];
    binit[3][r] = b_c[hc0 + r];
  }

  // zero hbuf[0]: 16 rows x 128 cols via b64 per thread
  {
    const int zr = tid >> 5, zc = (tid & 31) << 2;
    *(unsigned long long*)(&hbuf[0][zr * PITCH + zc]) = 0ull;
  }

  // x fragment base for this lane: row n0+lr, cols lh*8 + kk*32 (+ t*32768)
  const unsigned short* xlane =
      xbf + ((size_t)(bb * 128) * 256 + n0 + lr) * 128 + lh * 8;

  bf16x8 xA[4], xB[4];
#pragma unroll
  for (int kk = 0; kk < 4; ++kk) xA[kk] = *(const bf16x8*)(xlane + kk * 32);

  float cr[4] = {0.f, 0.f, 0.f, 0.f};
  __syncthreads();

// Zero-cost register pin: "+v" makes these VALUES live in VGPRs at this point
// each iteration -> the barrier's "memory" clobber can't force re-loads.
#define PIN4(a, b, c, d) \
  asm volatile("" : "+v"(a), "+v"(b), "+v"(c), "+v"(d))
#define PIN_STATE()                                                   \
  PIN4(Wf[0][0], Wf[0][1], Wf[0][2], Wf[0][3]);                       \
  PIN4(Wf[0][4], Wf[0][5], Wf[0][6], Wf[0][7]);                       \
  PIN4(Wf[1][0], Wf[1][1], Wf[1][2], Wf[1][3]);                       \
  PIN4(Wf[1][4], Wf[1][5], Wf[1][6], Wf[1][7]);                       \
  PIN4(Wf[2][0], Wf[2][1], Wf[2][2], Wf[2][3]);                       \
  PIN4(Wf[2][4], Wf[2][5], Wf[2][6], Wf[2][7]);                       \
  PIN4(Wf[3][0], Wf[3][1], Wf[3][2], Wf[3][3]);                       \
  PIN4(Wf[3][4], Wf[3][5], Wf[3][6], Wf[3][7]);                       \
  PIN4(binit[0], binit[1], binit[2], binit[3])

#define STEP(T, XC, XN)                                                        \
  {                                                                            \
    PIN_STATE();                                                               \
    const int cur = (T) & 1, nxt = cur ^ 1;                                    \
    const int tp = ((T) + 1 < 128) ? (T) + 1 : 127;                            \
    _Pragma("unroll")                                                          \
    for (int kk = 0; kk < 4; ++kk)                                             \
      XN[kk] = *(const bf16x8*)(xlane + (size_t)tp * 32768 + kk * 32);         \
    bf16x8 hf[4];                                                              \
    _Pragma("unroll")                                                          \
    for (int kk = 0; kk < 4; ++kk)                                             \
      hf[kk] = *(const bf16x8*)(&hbuf[cur][lr * PITCH + lh * 8 + kk * 32]);    \
    f32x4 acc[4];                                                              \
    _Pragma("unroll")                                                          \
    for (int g = 0; g < 4; ++g) {                                              \
      f32x4 a_ = binit[g];                                                     \
      _Pragma("unroll")                                                        \
      for (int kk = 0; kk < 4; ++kk)                                           \
        a_ = __builtin_amdgcn_mfma_f32_16x16x32_bf16(Wf[g][kk + 4], XC[kk],    \
                                                     a_, 0, 0, 0);             \
      _Pragma("unroll")                                                        \
      for (int kk = 0; kk < 4; ++kk)                                           \
        a_ = __builtin_amdgcn_mfma_f32_16x16x32_bf16(Wf[g][kk], hf[kk],        \
                                                     a_, 0, 0, 0);             \
      acc[g] = a_;                                                             \
    }                                                                          \
    float4 ov;                                                                 \
    unsigned long long hp = 0ull;                                              \
    _Pragma("unroll")                                                          \
    for (int r = 0; r < 4; ++r) {                                              \
      const float iv = sigm(acc[0][r]);                                        \
      const float fv = sigm(acc[1][r]);                                        \
      const float o_ = sigm(acc[2][r]);                                        \
      const float gv = tanh_(acc[3][r]);                                       \
      const float cn = fv * cr[r] + iv * gv;                                   \
      cr[r] = cn;                                                              \
      const float hv = o_ * tanh_(cn);                                         \
      ((float*)&ov)[r] = hv;                                                   \
      hp |= (unsigned long long)f2bf(hv) << (16 * r);                          \
    }                                                                          \
    *(float4*)(out + ((size_t)((T) * 16 + bb) * 256 + n0 + lr) * 128 + hc0) =  \
        ov;                                                                    \
    *(unsigned long long*)(&hbuf[nxt][lr * PITCH + hc0]) = hp;                 \
    asm volatile("s_waitcnt lgkmcnt(0)\n\ts_barrier" ::: "memory");            \
    __builtin_amdgcn_sched_barrier(0);                                         \
  }

  for (int t = 0; t < 128; t += 2) {
    STEP(t, xA, xB)
    STEP(t + 1, xB, xA)
  }
#undef STEP
#undef PIN_STATE
#undef PIN4
}

extern "C" void kernel_launch(void* const* d_in, const int* in_sizes, int n_in,
                              void* d_out, int out_size, void* d_ws, size_t ws_size,
                              hipStream_t stream) {
  (void)in_sizes; (void)n_in; (void)out_size; (void)ws_size;
  // setup_inputs order: 0:x 1:Wix 2:Wim 3:Wfx 4:Wfm 5:Wcx 6:Wcm 7:Wox 8:Wom
  //                     9:bi 10:bf 11:bc 12:bo   (note: bc before bo)
  const float* x   = (const float*)d_in[0];
  const float* Wix = (const float*)d_in[1];
  const float* Wim = (const float*)d_in[2];
  const float* Wfx = (const float*)d_in[3];
  const float* Wfm = (const float*)d_in[4];
  const float* Wcx = (const float*)d_in[5];
  const float* Wcm = (const float*)d_in[6];
  const float* Wox = (const float*)d_in[7];
  const float* Wom = (const float*)d_in[8];
  const float* bi  = (const float*)d_in[9];
  const float* bf  = (const float*)d_in[10];
  const float* bc  = (const float*)d_in[11];
  const float* bo  = (const float*)d_in[12];

  char* ws = (char*)d_ws;
  unsigned short* WT  = (unsigned short*)ws;               // 256 KB
  unsigned short* xbf = (unsigned short*)(ws + (1 << 20)); // 134 MB
  float* out = (float*)d_out;

  pack_w<<<512, 256, 0, stream>>>(Wim, Wfm, Wom, Wcm, Wix, Wfx, Wox, Wcx, WT);
  xcvt<<<32768, 256, 0, stream>>>(x, xbf);
  lstm_persist<<<256, 512, 0, stream>>>(xbf, WT, bi, bf, bo, bc, out);
}